// Round 1
// baseline (449.115 us; speedup 1.0000x reference)
//
#include <hip/hip_runtime.h>
#include <math.h>

#define N_NODES 50000
#define N_EDGES 800000
#define F_IN 64
#define HEADS 4
#define C_OUT 64
#define GEMM_ROWS 16

// ---------------------------------------------------------------------------
// K1: T[N][512] : cols 0..255 = x @ W_lin (xs), cols 256..511 = x @ W_att (u)
// 16 rows per block, 256 threads. W rows streamed from L2 (128 KB total).
// ---------------------------------------------------------------------------
__global__ __launch_bounds__(256) void gemm_kernel(
    const float* __restrict__ x, const float* __restrict__ Wlin,
    const float* __restrict__ Watt, float* __restrict__ T) {
  __shared__ float xlds[GEMM_ROWS * 64];
  const int tid = threadIdx.x;
  const int blk = blockIdx.x;
#pragma unroll
  for (int q = 0; q < GEMM_ROWS * 64 / 256; ++q)
    xlds[q * 256 + tid] = x[(size_t)blk * GEMM_ROWS * 64 + q * 256 + tid];
  __syncthreads();

  const int c4 = tid & 127;          // float4 column chunk 0..127 (512 cols)
  const int rg = (tid >> 7) * 8;     // row base within block: 0 or 8
  const float4* wbase = (c4 < 64) ? ((const float4*)Wlin) + c4
                                  : ((const float4*)Watt) + (c4 - 64);
  float4 acc[8] = {};
  for (int k = 0; k < 64; ++k) {
    float4 w4 = wbase[(size_t)k * 64];  // W row stride = 256 floats = 64 float4
#pragma unroll
    for (int r = 0; r < 8; ++r) {
      float a = xlds[(rg + r) * 64 + k];
      acc[r].x += a * w4.x; acc[r].y += a * w4.y;
      acc[r].z += a * w4.z; acc[r].w += a * w4.w;
    }
  }
  float4* Tv = (float4*)T;
  const int rowbase = blk * GEMM_ROWS + rg;
#pragma unroll
  for (int r = 0; r < 8; ++r)
    Tv[(size_t)(rowbase + r) * 128 + c4] = acc[r];
}

// ---------------------------------------------------------------------------
// K2: degree histogram over dst
// ---------------------------------------------------------------------------
__global__ __launch_bounds__(256) void hist_kernel(const int* __restrict__ dst,
                                                   int* __restrict__ deg) {
  int e = blockIdx.x * 256 + threadIdx.x;
  if (e < N_EDGES) atomicAdd(&deg[dst[e]], 1);
}

// ---------------------------------------------------------------------------
// K3: exclusive scan of deg -> offs (single block, 1024 threads, 49 items/thr)
// ---------------------------------------------------------------------------
#define SCAN_THREADS 1024
__global__ __launch_bounds__(SCAN_THREADS) void scan_kernel(
    const int* __restrict__ deg, int* __restrict__ offs) {
  __shared__ int tmp[SCAN_THREADS];
  const int per = (N_NODES + SCAN_THREADS - 1) / SCAN_THREADS;  // 49
  const int tid = threadIdx.x;
  const int base = tid * per;
  int sum = 0;
  for (int q = 0; q < per; ++q) {
    int idx = base + q;
    if (idx < N_NODES) sum += deg[idx];
  }
  tmp[tid] = sum;
  __syncthreads();
  for (int d = 1; d < SCAN_THREADS; d <<= 1) {
    int t = (tid >= d) ? tmp[tid - d] : 0;
    __syncthreads();
    tmp[tid] += t;
    __syncthreads();
  }
  int run = tmp[tid] - sum;  // exclusive prefix for this thread's range
  for (int q = 0; q < per; ++q) {
    int idx = base + q;
    if (idx < N_NODES) { offs[idx] = run; run += deg[idx]; }
  }
  if (tid == SCAN_THREADS - 1) offs[N_NODES] = tmp[SCAN_THREADS - 1];
}

// ---------------------------------------------------------------------------
// K4: scatter edges into CSR order (src id + weight packed CSR-side)
// ---------------------------------------------------------------------------
__global__ __launch_bounds__(256) void scatter_kernel(
    const int* __restrict__ src, const int* __restrict__ dst,
    const float* __restrict__ ew, const int* __restrict__ offs,
    int* __restrict__ cursor, int* __restrict__ csr_src,
    float* __restrict__ csr_w) {
  int e = blockIdx.x * 256 + threadIdx.x;
  if (e >= N_EDGES) return;
  int d = dst[e];
  int pos = atomicAdd(&cursor[d], 1);
  int idx = offs[d] + pos;
  csr_src[idx] = src[e];
  csr_w[idx] = ew[e];
}

// ---------------------------------------------------------------------------
// K5: per-node aggregation. One wave per node.
// Lane layout: lane = h*16 + l ; lane owns float4 chunk l of head h (F=C=64).
// Online softmax (running max m, denom lsum, acc) == reference two-pass math.
// ---------------------------------------------------------------------------
__global__ __launch_bounds__(256) void aggregate_kernel(
    const float* __restrict__ T, const float* __restrict__ x,
    const int* __restrict__ offs, const int* __restrict__ csr_src,
    const float* __restrict__ csr_w, const float* __restrict__ bias,
    float* __restrict__ out) {
  int gtid = blockIdx.x * 256 + threadIdx.x;
  int node = gtid >> 6;
  if (node >= N_NODES) return;
  const int lane = threadIdx.x & 63;
  const int l = lane & 15;
  const int h = lane >> 4;

  // x_i chunk (raw input features of the destination node)
  float4 xi = ((const float4*)(x + (size_t)node * 64))[l];

  const int s0 = offs[node];
  const int s1 = offs[node + 1];
  const float4* Tv = (const float4*)T;

  float m = -INFINITY;
  float lsum = 0.f;
  float4 acc = {0.f, 0.f, 0.f, 0.f};

  for (int k = s0; k < s1; ++k) {
    int j = csr_src[k];       // wave-uniform
    float w = csr_w[k];       // wave-uniform
    // u[j][h][4l..4l+3] : T row j, cols 256 + h*64 + 4l
    float4 uv = Tv[(size_t)j * 128 + 64 + h * 16 + l];
    float s = uv.x * xi.x + uv.y * xi.y + uv.z * xi.z + uv.w * xi.w;
    s += __shfl_xor(s, 1);
    s += __shfl_xor(s, 2);
    s += __shfl_xor(s, 4);
    s += __shfl_xor(s, 8);    // all 16 lanes of head-group h now hold dot
    s *= 0.125f;              // / sqrt(64)
    s = (s > 0.f) ? s : 0.2f * s;  // leaky_relu
    float mn = fmaxf(m, s);
    float corr = __expf(m - mn);   // m=-inf first iter -> corr=0
    float p = __expf(s - mn) * w;  // mask = edge_weight
    // xs[j][h][4l..4l+3] : T row j, cols h*64 + 4l
    float4 xv = Tv[(size_t)j * 128 + h * 16 + l];
    lsum = lsum * corr + p;
    acc.x = acc.x * corr + p * xv.x;
    acc.y = acc.y * corr + p * xv.y;
    acc.z = acc.z * corr + p * xv.z;
    acc.w = acc.w * corr + p * xv.w;
    m = mn;
  }
  float inv = 1.f / (lsum + 1e-16f);
  float4 bv = ((const float4*)bias)[h * 16 + l];
  float4 o;
  o.x = acc.x * inv + bv.x;
  o.y = acc.y * inv + bv.y;
  o.z = acc.z * inv + bv.z;
  o.w = acc.w * inv + bv.w;
  ((float4*)out)[(size_t)node * 64 + h * 16 + l] = o;
}

// ---------------------------------------------------------------------------
extern "C" void kernel_launch(void* const* d_in, const int* in_sizes, int n_in,
                              void* d_out, int out_size, void* d_ws,
                              size_t ws_size, hipStream_t stream) {
  (void)in_sizes; (void)n_in; (void)out_size; (void)ws_size;
  const float* x    = (const float*)d_in[0];
  const int*   ei   = (const int*)d_in[1];
  const float* ew   = (const float*)d_in[2];
  const float* Wlin = (const float*)d_in[3];
  const float* Watt = (const float*)d_in[4];
  const float* bias = (const float*)d_in[5];
  float* out = (float*)d_out;

  const int* srcv = ei;            // edge_index[0]
  const int* dstv = ei + N_EDGES;  // edge_index[1]

  // workspace carve-up (256B aligned)
  char* ws = (char*)d_ws;
  size_t off = 0;
  auto alloc = [&](size_t bytes) {
    void* p = ws + off;
    off += (bytes + 255) & ~(size_t)255;
    return p;
  };
  float* T       = (float*)alloc((size_t)N_NODES * 512 * 4);  // 102.4 MB
  int*   deg     = (int*)alloc((size_t)N_NODES * 4);
  int*   cursor  = (int*)alloc((size_t)N_NODES * 4);
  int*   offs    = (int*)alloc((size_t)(N_NODES + 1) * 4);
  int*   csr_src = (int*)alloc((size_t)N_EDGES * 4);
  float* csr_w   = (float*)alloc((size_t)N_EDGES * 4);

  hipMemsetAsync(deg, 0, (size_t)N_NODES * 4, stream);
  hipMemsetAsync(cursor, 0, (size_t)N_NODES * 4, stream);

  gemm_kernel<<<N_NODES / GEMM_ROWS, 256, 0, stream>>>(x, Wlin, Watt, T);
  hist_kernel<<<(N_EDGES + 255) / 256, 256, 0, stream>>>(dstv, deg);
  scan_kernel<<<1, SCAN_THREADS, 0, stream>>>(deg, offs);
  scatter_kernel<<<(N_EDGES + 255) / 256, 256, 0, stream>>>(
      srcv, dstv, ew, offs, cursor, csr_src, csr_w);
  aggregate_kernel<<<(N_NODES * 64 + 255) / 256, 256, 0, stream>>>(
      T, x, offs, csr_src, csr_w, bias, out);
}

// Round 2
// 391.721 us; speedup vs baseline: 1.1465x; 1.1465x over previous
//
#include <hip/hip_runtime.h>
#include <math.h>

#define N_NODES 50000
#define N_EDGES 800000
#define GEMM_ROWS 16

// ---------------------------------------------------------------------------
// K0: transpose W_att (per head block): Wt[f, h*64+g] = W_att[g, h*64+f]
// so that q[i, h*64+g] = sum_f x[i,f] * Wt[f, h*64+g] = (W_att_h @ x_i)[g]
// ---------------------------------------------------------------------------
__global__ __launch_bounds__(256) void transpose_watt_kernel(
    const float* __restrict__ Watt, float* __restrict__ Wt) {
  int e = blockIdx.x * 256 + threadIdx.x;  // 16384 elements
  int g = e & 63;
  int f = (e >> 6) & 63;
  int h = e >> 12;
  Wt[f * 256 + h * 64 + g] = Watt[g * 256 + h * 64 + f];
}

// ---------------------------------------------------------------------------
// K1: q = x @ Wt  -> [N, 256]. 16 rows/block, 256 threads.
// ---------------------------------------------------------------------------
__global__ __launch_bounds__(256) void qgemm_kernel(
    const float* __restrict__ x, const float* __restrict__ Wt,
    float* __restrict__ q) {
  __shared__ float xlds[GEMM_ROWS * 64];
  const int tid = threadIdx.x;
  const int blk = blockIdx.x;
#pragma unroll
  for (int p = 0; p < GEMM_ROWS * 64 / 256; ++p)
    xlds[p * 256 + tid] = x[(size_t)blk * GEMM_ROWS * 64 + p * 256 + tid];
  __syncthreads();

  const int c4 = tid & 63;       // float4 col chunk 0..63 (256 cols)
  const int rg = (tid >> 6) * 4; // row base 0,4,8,12
  const float4* Wv = (const float4*)Wt;
  float4 acc[4] = {};
  for (int k = 0; k < 64; ++k) {
    float4 w4 = Wv[(size_t)k * 64 + c4];
#pragma unroll
    for (int r = 0; r < 4; ++r) {
      float a = xlds[(rg + r) * 64 + k];
      acc[r].x += a * w4.x; acc[r].y += a * w4.y;
      acc[r].z += a * w4.z; acc[r].w += a * w4.w;
    }
  }
  float4* qv = (float4*)q;
#pragma unroll
  for (int r = 0; r < 4; ++r)
    qv[(size_t)(blk * GEMM_ROWS + rg + r) * 64 + c4] = acc[r];
}

// ---------------------------------------------------------------------------
// K2: degree histogram over dst
// ---------------------------------------------------------------------------
__global__ __launch_bounds__(256) void hist_kernel(const int* __restrict__ dst,
                                                   int* __restrict__ deg) {
  int e = blockIdx.x * 256 + threadIdx.x;
  if (e < N_EDGES) atomicAdd(&deg[dst[e]], 1);
}

// ---------------------------------------------------------------------------
// K3: exclusive scan of deg -> offs (single block)
// ---------------------------------------------------------------------------
#define SCAN_THREADS 1024
__global__ __launch_bounds__(SCAN_THREADS) void scan_kernel(
    const int* __restrict__ deg, int* __restrict__ offs) {
  __shared__ int tmp[SCAN_THREADS];
  const int per = (N_NODES + SCAN_THREADS - 1) / SCAN_THREADS;  // 49
  const int tid = threadIdx.x;
  const int base = tid * per;
  int sum = 0;
  for (int p = 0; p < per; ++p) {
    int idx = base + p;
    if (idx < N_NODES) sum += deg[idx];
  }
  tmp[tid] = sum;
  __syncthreads();
  for (int d = 1; d < SCAN_THREADS; d <<= 1) {
    int t = (tid >= d) ? tmp[tid - d] : 0;
    __syncthreads();
    tmp[tid] += t;
    __syncthreads();
  }
  int run = tmp[tid] - sum;
  for (int p = 0; p < per; ++p) {
    int idx = base + p;
    if (idx < N_NODES) { offs[idx] = run; run += deg[idx]; }
  }
  if (tid == SCAN_THREADS - 1) offs[N_NODES] = tmp[SCAN_THREADS - 1];
}

// ---------------------------------------------------------------------------
// K4: scatter edges into CSR order
// ---------------------------------------------------------------------------
__global__ __launch_bounds__(256) void scatter_kernel(
    const int* __restrict__ src, const int* __restrict__ dst,
    const float* __restrict__ ew, const int* __restrict__ offs,
    int* __restrict__ cursor, int* __restrict__ csr_src,
    float* __restrict__ csr_w) {
  int e = blockIdx.x * 256 + threadIdx.x;
  if (e >= N_EDGES) return;
  int d = dst[e];
  int pos = atomicAdd(&cursor[d], 1);
  int idx = offs[d] + pos;
  csr_src[idx] = src[e];
  csr_w[idx] = ew[e];
}

// ---------------------------------------------------------------------------
// K5: fused aggregation (online softmax over raw x[src]) + output GEMM.
// One wave per node (4 nodes/block). Lane = h*16 + l; lane owns x chunk l,
// q chunk (h, 4l..4l+3).
// Phase 2: normalized per-head agg staged in LDS, then out = agg @ W_lin_h.
// ---------------------------------------------------------------------------
__global__ __launch_bounds__(256) void aggregate_kernel(
    const float* __restrict__ q, const float* __restrict__ x,
    const int* __restrict__ offs, const int* __restrict__ csr_src,
    const float* __restrict__ csr_w, const float* __restrict__ Wlin,
    const float* __restrict__ bias, float* __restrict__ out) {
  __shared__ float agg_lds[4][256];
  const int wave = threadIdx.x >> 6;
  const int node = blockIdx.x * 4 + wave;   // grid sized so node < N_NODES
  const int lane = threadIdx.x & 63;
  const int l = lane & 15;
  const int h = lane >> 4;

  // q chunk for this head: q[node, h*64 + 4l .. 4l+3]
  float4 qi = ((const float4*)q)[(size_t)node * 64 + h * 16 + l];

  const int s0 = offs[node];
  const int s1 = offs[node + 1];
  const float4* xv = (const float4*)x;

  float m = -INFINITY;
  float lsum = 0.f;
  float4 acc = {0.f, 0.f, 0.f, 0.f};

  for (int k = s0; k < s1; ++k) {
    int j = csr_src[k];
    float w = csr_w[k];
    float4 xj = xv[(size_t)j * 16 + l];
    float s = xj.x * qi.x + xj.y * qi.y + xj.z * qi.z + xj.w * qi.w;
    s += __shfl_xor(s, 1);
    s += __shfl_xor(s, 2);
    s += __shfl_xor(s, 4);
    s += __shfl_xor(s, 8);     // 16-lane head-group reduction
    s *= 0.125f;               // / sqrt(64)
    s = (s > 0.f) ? s : 0.2f * s;
    float mn = fmaxf(m, s);
    float corr = __expf(m - mn);
    float p = __expf(s - mn) * w;
    lsum = lsum * corr + p;
    acc.x = acc.x * corr + p * xj.x;
    acc.y = acc.y * corr + p * xj.y;
    acc.z = acc.z * corr + p * xj.z;
    acc.w = acc.w * corr + p * xj.w;
    m = mn;
  }
  float inv = 1.f / (lsum + 1e-16f);
  float4 an;
  an.x = acc.x * inv; an.y = acc.y * inv;
  an.z = acc.z * inv; an.w = acc.w * inv;
  ((float4*)agg_lds[wave])[h * 16 + l] = an;
  __syncthreads();

  // Phase 2: out[node_r, 4*c4..] = agg[r, hh] @ W_lin_hh + bias
  const int c4 = threadIdx.x & 63;   // output col chunk
  const int r = threadIdx.x >> 6;    // which node in block
  const int hh = c4 >> 4;
  const float4* Wv = (const float4*)Wlin;
  float4 o = ((const float4*)bias)[c4];
  const float* arow = agg_lds[r] + hh * 64;
#pragma unroll 4
  for (int g = 0; g < 64; ++g) {
    float a = arow[g];
    float4 w4 = Wv[(size_t)g * 64 + c4];
    o.x += a * w4.x; o.y += a * w4.y;
    o.z += a * w4.z; o.w += a * w4.w;
  }
  ((float4*)out)[(size_t)(blockIdx.x * 4 + r) * 64 + c4] = o;
}

// ---------------------------------------------------------------------------
extern "C" void kernel_launch(void* const* d_in, const int* in_sizes, int n_in,
                              void* d_out, int out_size, void* d_ws,
                              size_t ws_size, hipStream_t stream) {
  (void)in_sizes; (void)n_in; (void)out_size; (void)ws_size;
  const float* x    = (const float*)d_in[0];
  const int*   ei   = (const int*)d_in[1];
  const float* ew   = (const float*)d_in[2];
  const float* Wlin = (const float*)d_in[3];
  const float* Watt = (const float*)d_in[4];
  const float* bias = (const float*)d_in[5];
  float* out = (float*)d_out;

  const int* srcv = ei;            // edge_index[0]
  const int* dstv = ei + N_EDGES;  // edge_index[1]

  char* ws = (char*)d_ws;
  size_t off = 0;
  auto alloc = [&](size_t bytes) {
    void* p = ws + off;
    off += (bytes + 255) & ~(size_t)255;
    return p;
  };
  float* q       = (float*)alloc((size_t)N_NODES * 256 * 4);  // 51.2 MB
  float* Wt      = (float*)alloc((size_t)64 * 256 * 4);
  int*   deg     = (int*)alloc((size_t)N_NODES * 4);
  int*   cursor  = (int*)alloc((size_t)N_NODES * 4);
  int*   offs    = (int*)alloc((size_t)(N_NODES + 1) * 4);
  int*   csr_src = (int*)alloc((size_t)N_EDGES * 4);
  float* csr_w   = (float*)alloc((size_t)N_EDGES * 4);

  hipMemsetAsync(deg, 0, (size_t)N_NODES * 4, stream);
  hipMemsetAsync(cursor, 0, (size_t)N_NODES * 4, stream);

  transpose_watt_kernel<<<64, 256, 0, stream>>>(Watt, Wt);
  qgemm_kernel<<<N_NODES / GEMM_ROWS + (N_NODES % GEMM_ROWS ? 1 : 0), 256, 0,
                 stream>>>(x, Wt, q);
  hist_kernel<<<(N_EDGES + 255) / 256, 256, 0, stream>>>(dstv, deg);
  scan_kernel<<<1, SCAN_THREADS, 0, stream>>>(deg, offs);
  scatter_kernel<<<(N_EDGES + 255) / 256, 256, 0, stream>>>(
      srcv, dstv, ew, offs, cursor, csr_src, csr_w);
  aggregate_kernel<<<N_NODES / 4, 256, 0, stream>>>(
      q, x, offs, csr_src, csr_w, Wlin, bias, out);
}

// Round 3
// 286.720 us; speedup vs baseline: 1.5664x; 1.3662x over previous
//
#include <hip/hip_runtime.h>
#include <math.h>

#define N_NODES 50000
#define N_EDGES 800000
#define GEMM_ROWS 16
#define AGG_NODES 32

// ---------------------------------------------------------------------------
// K0: transpose W_att per head block: Wt[f, h*64+g] = W_att[g, h*64+f]
// so q[i, h*64+g] = (W_att_h @ x_i)[g]
// ---------------------------------------------------------------------------
__global__ __launch_bounds__(256) void transpose_watt_kernel(
    const float* __restrict__ Watt, float* __restrict__ Wt) {
  int e = blockIdx.x * 256 + threadIdx.x;  // 16384 elements
  int g = e & 63;
  int f = (e >> 6) & 63;
  int h = e >> 12;
  Wt[f * 256 + h * 64 + g] = Watt[g * 256 + h * 64 + f];
}

// ---------------------------------------------------------------------------
// K1: q = x @ Wt -> [N, 256]
// ---------------------------------------------------------------------------
__global__ __launch_bounds__(256) void qgemm_kernel(
    const float* __restrict__ x, const float* __restrict__ Wt,
    float* __restrict__ q) {
  __shared__ float xlds[GEMM_ROWS * 64];
  const int tid = threadIdx.x;
  const int blk = blockIdx.x;
#pragma unroll
  for (int p = 0; p < GEMM_ROWS * 64 / 256; ++p)
    xlds[p * 256 + tid] = x[(size_t)blk * GEMM_ROWS * 64 + p * 256 + tid];
  __syncthreads();

  const int c4 = tid & 63;
  const int rg = (tid >> 6) * 4;
  const float4* Wv = (const float4*)Wt;
  float4 acc[4] = {};
  for (int k = 0; k < 64; ++k) {
    float4 w4 = Wv[(size_t)k * 64 + c4];
#pragma unroll
    for (int r = 0; r < 4; ++r) {
      float a = xlds[(rg + r) * 64 + k];
      acc[r].x += a * w4.x; acc[r].y += a * w4.y;
      acc[r].z += a * w4.z; acc[r].w += a * w4.w;
    }
  }
  float4* qv = (float4*)q;
#pragma unroll
  for (int r = 0; r < 4; ++r)
    qv[(size_t)(blk * GEMM_ROWS + rg + r) * 64 + c4] = acc[r];
}

// ---------------------------------------------------------------------------
// K2: degree histogram over dst + per-edge intra-segment position
// ---------------------------------------------------------------------------
__global__ __launch_bounds__(256) void hist_kernel(const int* __restrict__ dst,
                                                   int* __restrict__ deg,
                                                   int* __restrict__ epos) {
  int e = blockIdx.x * 256 + threadIdx.x;
  if (e < N_EDGES) epos[e] = atomicAdd(&deg[dst[e]], 1);
}

// ---------------------------------------------------------------------------
// K3: exclusive scan of deg -> offs (single block)
// ---------------------------------------------------------------------------
#define SCAN_THREADS 1024
__global__ __launch_bounds__(SCAN_THREADS) void scan_kernel(
    const int* __restrict__ deg, int* __restrict__ offs) {
  __shared__ int tmp[SCAN_THREADS];
  const int per = (N_NODES + SCAN_THREADS - 1) / SCAN_THREADS;  // 49
  const int tid = threadIdx.x;
  const int base = tid * per;
  int sum = 0;
  for (int p = 0; p < per; ++p) {
    int idx = base + p;
    if (idx < N_NODES) sum += deg[idx];
  }
  tmp[tid] = sum;
  __syncthreads();
  for (int d = 1; d < SCAN_THREADS; d <<= 1) {
    int t = (tid >= d) ? tmp[tid - d] : 0;
    __syncthreads();
    tmp[tid] += t;
    __syncthreads();
  }
  int run = tmp[tid] - sum;
  for (int p = 0; p < per; ++p) {
    int idx = base + p;
    if (idx < N_NODES) { offs[idx] = run; run += deg[idx]; }
  }
  if (tid == SCAN_THREADS - 1) offs[N_NODES] = tmp[SCAN_THREADS - 1];
}

// ---------------------------------------------------------------------------
// K4: scatter edges into CSR order (no atomics; uses epos)
// ---------------------------------------------------------------------------
__global__ __launch_bounds__(256) void scatter_kernel(
    const int* __restrict__ src, const int* __restrict__ dst,
    const float* __restrict__ ew, const int* __restrict__ offs,
    const int* __restrict__ epos, int* __restrict__ csr_src,
    float* __restrict__ csr_w) {
  int e = blockIdx.x * 256 + threadIdx.x;
  if (e >= N_EDGES) return;
  int idx = offs[dst[e]] + epos[e];
  csr_src[idx] = src[e];
  csr_w[idx] = ew[e];
}

// ---------------------------------------------------------------------------
// K5: aggregation only (online softmax over raw x[src]), 4-edge batched.
// One wave per node. Lane = h*16+l. Writes agg[N,256] (pre-W_lin).
// ---------------------------------------------------------------------------
__global__ __launch_bounds__(256) void aggregate_kernel(
    const float* __restrict__ q, const float* __restrict__ x,
    const int* __restrict__ offs, const int* __restrict__ csr_src,
    const float* __restrict__ csr_w, float* __restrict__ agg) {
  const int wave = threadIdx.x >> 6;
  const int node = blockIdx.x * 4 + wave;  // grid exact: 50000 = 4*12500
  const int lane = threadIdx.x & 63;
  const int l = lane & 15;
  const int h = lane >> 4;

  float4 qi = ((const float4*)q)[(size_t)node * 64 + h * 16 + l];

  const int s0 = offs[node];
  const int s1 = offs[node + 1];
  const float4* xv = (const float4*)x;

  float m = -INFINITY;
  float lsum = 0.f;
  float4 acc = {0.f, 0.f, 0.f, 0.f};

  int k = s0;
  for (; k + 4 <= s1; k += 4) {
    int j0 = csr_src[k + 0], j1 = csr_src[k + 1];
    int j2 = csr_src[k + 2], j3 = csr_src[k + 3];
    float w0 = csr_w[k + 0], w1 = csr_w[k + 1];
    float w2 = csr_w[k + 2], w3 = csr_w[k + 3];
    float4 a0 = xv[(size_t)j0 * 16 + l];
    float4 a1 = xv[(size_t)j1 * 16 + l];
    float4 a2 = xv[(size_t)j2 * 16 + l];
    float4 a3 = xv[(size_t)j3 * 16 + l];
    float t0 = a0.x * qi.x + a0.y * qi.y + a0.z * qi.z + a0.w * qi.w;
    float t1 = a1.x * qi.x + a1.y * qi.y + a1.z * qi.z + a1.w * qi.w;
    float t2 = a2.x * qi.x + a2.y * qi.y + a2.z * qi.z + a2.w * qi.w;
    float t3 = a3.x * qi.x + a3.y * qi.y + a3.z * qi.z + a3.w * qi.w;
#pragma unroll
    for (int d = 1; d <= 8; d <<= 1) {
      t0 += __shfl_xor(t0, d);
      t1 += __shfl_xor(t1, d);
      t2 += __shfl_xor(t2, d);
      t3 += __shfl_xor(t3, d);
    }
    t0 *= 0.125f; t1 *= 0.125f; t2 *= 0.125f; t3 *= 0.125f;
    t0 = (t0 > 0.f) ? t0 : 0.2f * t0;
    t1 = (t1 > 0.f) ? t1 : 0.2f * t1;
    t2 = (t2 > 0.f) ? t2 : 0.2f * t2;
    t3 = (t3 > 0.f) ? t3 : 0.2f * t3;
    float mx = fmaxf(fmaxf(t0, t1), fmaxf(t2, t3));
    float mn = fmaxf(m, mx);
    float corr = __expf(m - mn);
    float p0 = __expf(t0 - mn) * w0;
    float p1 = __expf(t1 - mn) * w1;
    float p2 = __expf(t2 - mn) * w2;
    float p3 = __expf(t3 - mn) * w3;
    lsum = lsum * corr + (p0 + p1 + p2 + p3);
    acc.x = acc.x * corr + p0 * a0.x + p1 * a1.x + p2 * a2.x + p3 * a3.x;
    acc.y = acc.y * corr + p0 * a0.y + p1 * a1.y + p2 * a2.y + p3 * a3.y;
    acc.z = acc.z * corr + p0 * a0.z + p1 * a1.z + p2 * a2.z + p3 * a3.z;
    acc.w = acc.w * corr + p0 * a0.w + p1 * a1.w + p2 * a2.w + p3 * a3.w;
    m = mn;
  }
  for (; k < s1; ++k) {
    int j = csr_src[k];
    float w = csr_w[k];
    float4 xj = xv[(size_t)j * 16 + l];
    float s = xj.x * qi.x + xj.y * qi.y + xj.z * qi.z + xj.w * qi.w;
    s += __shfl_xor(s, 1);
    s += __shfl_xor(s, 2);
    s += __shfl_xor(s, 4);
    s += __shfl_xor(s, 8);
    s *= 0.125f;
    s = (s > 0.f) ? s : 0.2f * s;
    float mn = fmaxf(m, s);
    float corr = __expf(m - mn);
    float p = __expf(s - mn) * w;
    lsum = lsum * corr + p;
    acc.x = acc.x * corr + p * xj.x;
    acc.y = acc.y * corr + p * xj.y;
    acc.z = acc.z * corr + p * xj.z;
    acc.w = acc.w * corr + p * xj.w;
    m = mn;
  }
  float inv = 1.f / (lsum + 1e-16f);
  float4 an;
  an.x = acc.x * inv; an.y = acc.y * inv;
  an.z = acc.z * inv; an.w = acc.w * inv;
  ((float4*)agg)[(size_t)node * 64 + h * 16 + l] = an;
}

// ---------------------------------------------------------------------------
// K6: out[n, hh*64+c] = agg[n, hh*64+:] @ Wlin[:, hh... block-diag] + bias
// 32 nodes/block; thread owns col-chunk c4 for 8 nodes -> Wlin read once per
// 32 nodes (register reuse), LDS tile padded [4][17] against bank conflicts.
// ---------------------------------------------------------------------------
__global__ __launch_bounds__(256) void out_gemm_kernel(
    const float* __restrict__ agg, const float* __restrict__ Wlin,
    const float* __restrict__ bias, float* __restrict__ out) {
  __shared__ float4 atile[AGG_NODES][4][17];  // [node][hh][g4] padded
  const int tid = threadIdx.x;
  const int node0 = blockIdx.x * AGG_NODES;
  const float4* av = (const float4*)agg;
#pragma unroll
  for (int p = 0; p < 8; ++p) {
    int idx = p * 256 + tid;  // 0..2047
    int row = idx >> 6;
    int c = idx & 63;
    if (node0 + row < N_NODES)
      atile[row][c >> 4][c & 15] = av[(size_t)(node0 + row) * 64 + c];
  }
  __syncthreads();
  const int c4 = tid & 63;
  const int ns = tid >> 6;  // nodes ns*8 .. ns*8+7
  const int hh = c4 >> 4;
  const float4* Wv = (const float4*)Wlin;
  float4 acc[8] = {};
  for (int g4 = 0; g4 < 16; ++g4) {
    float4 w0 = Wv[(size_t)(g4 * 4 + 0) * 64 + c4];
    float4 w1 = Wv[(size_t)(g4 * 4 + 1) * 64 + c4];
    float4 w2 = Wv[(size_t)(g4 * 4 + 2) * 64 + c4];
    float4 w3 = Wv[(size_t)(g4 * 4 + 3) * 64 + c4];
#pragma unroll
    for (int n = 0; n < 8; ++n) {
      float4 a = atile[ns * 8 + n][hh][g4];
      acc[n].x += a.x * w0.x + a.y * w1.x + a.z * w2.x + a.w * w3.x;
      acc[n].y += a.x * w0.y + a.y * w1.y + a.z * w2.y + a.w * w3.y;
      acc[n].z += a.x * w0.z + a.y * w1.z + a.z * w2.z + a.w * w3.z;
      acc[n].w += a.x * w0.w + a.y * w1.w + a.z * w2.w + a.w * w3.w;
    }
  }
  float4 bv = ((const float4*)bias)[c4];
#pragma unroll
  for (int n = 0; n < 8; ++n) {
    int node = node0 + ns * 8 + n;
    if (node < N_NODES) {
      float4 o;
      o.x = acc[n].x + bv.x; o.y = acc[n].y + bv.y;
      o.z = acc[n].z + bv.z; o.w = acc[n].w + bv.w;
      ((float4*)out)[(size_t)node * 64 + c4] = o;
    }
  }
}

// ---------------------------------------------------------------------------
extern "C" void kernel_launch(void* const* d_in, const int* in_sizes, int n_in,
                              void* d_out, int out_size, void* d_ws,
                              size_t ws_size, hipStream_t stream) {
  (void)in_sizes; (void)n_in; (void)out_size; (void)ws_size;
  const float* x    = (const float*)d_in[0];
  const int*   ei   = (const int*)d_in[1];
  const float* ew   = (const float*)d_in[2];
  const float* Wlin = (const float*)d_in[3];
  const float* Watt = (const float*)d_in[4];
  const float* bias = (const float*)d_in[5];
  float* out = (float*)d_out;

  const int* srcv = ei;
  const int* dstv = ei + N_EDGES;

  char* ws = (char*)d_ws;
  size_t off = 0;
  auto alloc = [&](size_t bytes) {
    void* p = ws + off;
    off += (bytes + 255) & ~(size_t)255;
    return p;
  };
  float* q       = (float*)alloc((size_t)N_NODES * 256 * 4);  // 51.2 MB
  float* agg     = (float*)alloc((size_t)N_NODES * 256 * 4);  // 51.2 MB
  float* Wt      = (float*)alloc((size_t)64 * 256 * 4);
  int*   deg     = (int*)alloc((size_t)N_NODES * 4);
  int*   offs    = (int*)alloc((size_t)(N_NODES + 1) * 4);
  int*   epos    = (int*)alloc((size_t)N_EDGES * 4);
  int*   csr_src = (int*)alloc((size_t)N_EDGES * 4);
  float* csr_w   = (float*)alloc((size_t)N_EDGES * 4);

  hipMemsetAsync(deg, 0, (size_t)N_NODES * 4, stream);

  transpose_watt_kernel<<<64, 256, 0, stream>>>(Watt, Wt);
  qgemm_kernel<<<(N_NODES + GEMM_ROWS - 1) / GEMM_ROWS, 256, 0, stream>>>(
      x, Wt, q);
  hist_kernel<<<(N_EDGES + 255) / 256, 256, 0, stream>>>(dstv, deg, epos);
  scan_kernel<<<1, SCAN_THREADS, 0, stream>>>(deg, offs);
  scatter_kernel<<<(N_EDGES + 255) / 256, 256, 0, stream>>>(
      srcv, dstv, ew, offs, epos, csr_src, csr_w);
  aggregate_kernel<<<N_NODES / 4, 256, 0, stream>>>(
      q, x, offs, csr_src, csr_w, agg);
  out_gemm_kernel<<<(N_NODES + AGG_NODES - 1) / AGG_NODES, 256, 0, stream>>>(
      agg, Wlin, bias, out);
}

// Round 4
// 219.263 us; speedup vs baseline: 2.0483x; 1.3077x over previous
//
#include <hip/hip_runtime.h>
#include <math.h>

#define N_NODES 50000
#define N_EDGES 800000
#define GEMM_ROWS 16
#define AGG_NODES 32
#define PAD_EDGES (N_EDGES + N_NODES * 7)   // 1,150,000 max padded slots
#define SCAN_BLOCKS 49                      // ceil(50000 / 1024)

// ---------------------------------------------------------------------------
// K0: transpose W_att per head block: Wt[f, h*64+g] = W_att[g, h*64+f]
// ---------------------------------------------------------------------------
__global__ __launch_bounds__(256) void transpose_watt_kernel(
    const float* __restrict__ Watt, float* __restrict__ Wt) {
  int e = blockIdx.x * 256 + threadIdx.x;  // 16384 elements
  int g = e & 63;
  int f = (e >> 6) & 63;
  int h = e >> 12;
  Wt[f * 256 + h * 64 + g] = Watt[g * 256 + h * 64 + f];
}

// ---------------------------------------------------------------------------
// K1: q = x @ Wt -> [N, 256]
// ---------------------------------------------------------------------------
__global__ __launch_bounds__(256) void qgemm_kernel(
    const float* __restrict__ x, const float* __restrict__ Wt,
    float* __restrict__ q) {
  __shared__ float xlds[GEMM_ROWS * 64];
  const int tid = threadIdx.x;
  const int blk = blockIdx.x;
#pragma unroll
  for (int p = 0; p < GEMM_ROWS * 64 / 256; ++p)
    xlds[p * 256 + tid] = x[(size_t)blk * GEMM_ROWS * 64 + p * 256 + tid];
  __syncthreads();

  const int c4 = tid & 63;
  const int rg = (tid >> 6) * 4;
  const float4* Wv = (const float4*)Wt;
  float4 acc[4] = {};
  for (int k = 0; k < 64; ++k) {
    float4 w4 = Wv[(size_t)k * 64 + c4];
#pragma unroll
    for (int r = 0; r < 4; ++r) {
      float a = xlds[(rg + r) * 64 + k];
      acc[r].x += a * w4.x; acc[r].y += a * w4.y;
      acc[r].z += a * w4.z; acc[r].w += a * w4.w;
    }
  }
  float4* qv = (float4*)q;
#pragma unroll
  for (int r = 0; r < 4; ++r)
    qv[(size_t)(blk * GEMM_ROWS + rg + r) * 64 + c4] = acc[r];
}

// ---------------------------------------------------------------------------
// K2: degree histogram over dst + per-edge intra-segment position
// ---------------------------------------------------------------------------
__global__ __launch_bounds__(256) void hist_kernel(const int* __restrict__ dst,
                                                   int* __restrict__ deg,
                                                   int* __restrict__ epos) {
  int e = blockIdx.x * 256 + threadIdx.x;
  if (e < N_EDGES) epos[e] = atomicAdd(&deg[dst[e]], 1);
}

// ---------------------------------------------------------------------------
// K3a: per-block sums of padded degrees (pad each segment to multiple of 8)
// 49 blocks x 256 threads x 4 elements
// ---------------------------------------------------------------------------
__global__ __launch_bounds__(256) void scan_partials_kernel(
    const int* __restrict__ deg, int* __restrict__ blocksums) {
  __shared__ int red[256];
  const int t = threadIdx.x;
  const int base = blockIdx.x * 1024 + t * 4;
  int s = 0;
  if (base + 3 < N_NODES) {
    int4 d = *(const int4*)(deg + base);
    s = ((d.x + 7) & ~7) + ((d.y + 7) & ~7) + ((d.z + 7) & ~7) +
        ((d.w + 7) & ~7);
  } else {
#pragma unroll
    for (int j = 0; j < 4; ++j)
      if (base + j < N_NODES) s += (deg[base + j] + 7) & ~7;
  }
  red[t] = s;
  __syncthreads();
  for (int d = 128; d > 0; d >>= 1) {
    if (t < d) red[t] += red[t + d];
    __syncthreads();
  }
  if (t == 0) blocksums[blockIdx.x] = red[0];
}

// ---------------------------------------------------------------------------
// K3b: exclusive scan of 49 block sums (one wave)
// ---------------------------------------------------------------------------
__global__ __launch_bounds__(64) void scan_blocksums_kernel(
    const int* __restrict__ blocksums, int* __restrict__ blockoffs) {
  const int t = threadIdx.x;
  int v = (t < SCAN_BLOCKS) ? blocksums[t] : 0;
  int inc = v;
#pragma unroll
  for (int d = 1; d < 64; d <<= 1) {
    int u = __shfl_up(inc, d);
    if (t >= d) inc += u;
  }
  if (t < SCAN_BLOCKS) blockoffs[t] = inc - v;
}

// ---------------------------------------------------------------------------
// K3c: final scan: offs[i] = blockoff + local exclusive prefix of padded deg
// ---------------------------------------------------------------------------
__global__ __launch_bounds__(256) void scan_final_kernel(
    const int* __restrict__ deg, const int* __restrict__ blockoffs,
    int* __restrict__ offs) {
  __shared__ int tsum[256];
  const int t = threadIdx.x;
  const int base = blockIdx.x * 1024 + t * 4;
  int d0 = 0, d1 = 0, d2 = 0, d3 = 0;
  if (base + 3 < N_NODES) {
    int4 d = *(const int4*)(deg + base);
    d0 = (d.x + 7) & ~7; d1 = (d.y + 7) & ~7;
    d2 = (d.z + 7) & ~7; d3 = (d.w + 7) & ~7;
  } else {
    if (base + 0 < N_NODES) d0 = (deg[base + 0] + 7) & ~7;
    if (base + 1 < N_NODES) d1 = (deg[base + 1] + 7) & ~7;
    if (base + 2 < N_NODES) d2 = (deg[base + 2] + 7) & ~7;
    if (base + 3 < N_NODES) d3 = (deg[base + 3] + 7) & ~7;
  }
  const int s = d0 + d1 + d2 + d3;
  int inc = s;
  tsum[t] = s;
  __syncthreads();
  for (int d = 1; d < 256; d <<= 1) {
    int u = (t >= d) ? tsum[t - d] : 0;
    __syncthreads();
    inc += u;
    tsum[t] = inc;
    __syncthreads();
  }
  int run = blockoffs[blockIdx.x] + inc - s;  // exclusive prefix
  if (base + 0 <= N_NODES) offs[base + 0] = run; run += d0;
  if (base + 1 <= N_NODES) offs[base + 1] = run; run += d1;
  if (base + 2 <= N_NODES) offs[base + 2] = run; run += d2;
  if (base + 3 <= N_NODES) offs[base + 3] = run;
}

// ---------------------------------------------------------------------------
// K4: scatter edges into padded-CSR order (no atomics; uses epos)
// padding slots keep their memset value: src=0, w=0 (zero contribution)
// ---------------------------------------------------------------------------
__global__ __launch_bounds__(256) void scatter_kernel(
    const int* __restrict__ src, const int* __restrict__ dst,
    const float* __restrict__ ew, const int* __restrict__ offs,
    const int* __restrict__ epos, int* __restrict__ csr_src,
    float* __restrict__ csr_w) {
  int e = blockIdx.x * 256 + threadIdx.x;
  if (e >= N_EDGES) return;
  int idx = offs[dst[e]] + epos[e];
  csr_src[idx] = src[e];
  csr_w[idx] = ew[e];
}

// ---------------------------------------------------------------------------
// K5: aggregation (softmax w/o max subtraction -- shift-invariant; scores are
// O(1) so exp(s) is safe in fp32). 8-edge batch, aligned int4/float4 csr
// loads, no tail (segments padded to x8 with w=0).
// One wave per node; lane owns float4 chunk (lane&15) of head (lane>>4).
// ---------------------------------------------------------------------------
__global__ __launch_bounds__(256) void aggregate_kernel(
    const float* __restrict__ q, const float* __restrict__ x,
    const int* __restrict__ offs, const int* __restrict__ csr_src,
    const float* __restrict__ csr_w, float* __restrict__ agg) {
  const int wave = threadIdx.x >> 6;
  const int node = blockIdx.x * 4 + wave;  // grid exact: 50000 = 4*12500
  const int lane = threadIdx.x & 63;
  const int l = lane & 15;

  float4 qi = ((const float4*)q)[(size_t)node * 64 + lane];

  const int s0 = offs[node];
  const int s1 = offs[node + 1];
  const int4* jv = (const int4*)csr_src;
  const float4* wv = (const float4*)csr_w;
  const float4* xv = (const float4*)x;

  float lsum = 0.f;
  float4 acc = {0.f, 0.f, 0.f, 0.f};

  for (int k = s0; k < s1; k += 8) {
    const int q4 = k >> 2;
    int4 ja = jv[q4];
    int4 jb = jv[q4 + 1];
    float4 wa = wv[q4];
    float4 wb = wv[q4 + 1];
    float4 a0 = xv[(size_t)ja.x * 16 + l];
    float4 a1 = xv[(size_t)ja.y * 16 + l];
    float4 a2 = xv[(size_t)ja.z * 16 + l];
    float4 a3 = xv[(size_t)ja.w * 16 + l];
    float4 a4 = xv[(size_t)jb.x * 16 + l];
    float4 a5 = xv[(size_t)jb.y * 16 + l];
    float4 a6 = xv[(size_t)jb.z * 16 + l];
    float4 a7 = xv[(size_t)jb.w * 16 + l];
    float t0 = a0.x * qi.x + a0.y * qi.y + a0.z * qi.z + a0.w * qi.w;
    float t1 = a1.x * qi.x + a1.y * qi.y + a1.z * qi.z + a1.w * qi.w;
    float t2 = a2.x * qi.x + a2.y * qi.y + a2.z * qi.z + a2.w * qi.w;
    float t3 = a3.x * qi.x + a3.y * qi.y + a3.z * qi.z + a3.w * qi.w;
    float t4 = a4.x * qi.x + a4.y * qi.y + a4.z * qi.z + a4.w * qi.w;
    float t5 = a5.x * qi.x + a5.y * qi.y + a5.z * qi.z + a5.w * qi.w;
    float t6 = a6.x * qi.x + a6.y * qi.y + a6.z * qi.z + a6.w * qi.w;
    float t7 = a7.x * qi.x + a7.y * qi.y + a7.z * qi.z + a7.w * qi.w;
#pragma unroll
    for (int d = 1; d <= 8; d <<= 1) {
      t0 += __shfl_xor(t0, d);
      t1 += __shfl_xor(t1, d);
      t2 += __shfl_xor(t2, d);
      t3 += __shfl_xor(t3, d);
      t4 += __shfl_xor(t4, d);
      t5 += __shfl_xor(t5, d);
      t6 += __shfl_xor(t6, d);
      t7 += __shfl_xor(t7, d);
    }
    t0 *= 0.125f; t1 *= 0.125f; t2 *= 0.125f; t3 *= 0.125f;
    t4 *= 0.125f; t5 *= 0.125f; t6 *= 0.125f; t7 *= 0.125f;
    t0 = (t0 > 0.f) ? t0 : 0.2f * t0;
    t1 = (t1 > 0.f) ? t1 : 0.2f * t1;
    t2 = (t2 > 0.f) ? t2 : 0.2f * t2;
    t3 = (t3 > 0.f) ? t3 : 0.2f * t3;
    t4 = (t4 > 0.f) ? t4 : 0.2f * t4;
    t5 = (t5 > 0.f) ? t5 : 0.2f * t5;
    t6 = (t6 > 0.f) ? t6 : 0.2f * t6;
    t7 = (t7 > 0.f) ? t7 : 0.2f * t7;
    float p0 = __expf(t0) * wa.x;
    float p1 = __expf(t1) * wa.y;
    float p2 = __expf(t2) * wa.z;
    float p3 = __expf(t3) * wa.w;
    float p4 = __expf(t4) * wb.x;
    float p5 = __expf(t5) * wb.y;
    float p6 = __expf(t6) * wb.z;
    float p7 = __expf(t7) * wb.w;
    lsum += ((p0 + p1) + (p2 + p3)) + ((p4 + p5) + (p6 + p7));
    acc.x += p0 * a0.x + p1 * a1.x + p2 * a2.x + p3 * a3.x +
             p4 * a4.x + p5 * a5.x + p6 * a6.x + p7 * a7.x;
    acc.y += p0 * a0.y + p1 * a1.y + p2 * a2.y + p3 * a3.y +
             p4 * a4.y + p5 * a5.y + p6 * a6.y + p7 * a7.y;
    acc.z += p0 * a0.z + p1 * a1.z + p2 * a2.z + p3 * a3.z +
             p4 * a4.z + p5 * a5.z + p6 * a6.z + p7 * a7.z;
    acc.w += p0 * a0.w + p1 * a1.w + p2 * a2.w + p3 * a3.w +
             p4 * a4.w + p5 * a5.w + p6 * a6.w + p7 * a7.w;
  }
  float inv = 1.f / (lsum + 1e-16f);
  float4 an;
  an.x = acc.x * inv; an.y = acc.y * inv;
  an.z = acc.z * inv; an.w = acc.w * inv;
  ((float4*)agg)[(size_t)node * 64 + lane] = an;
}

// ---------------------------------------------------------------------------
// K6: out[n, :] = agg[n, block-diag] @ Wlin + bias. 32 nodes/block.
// ---------------------------------------------------------------------------
__global__ __launch_bounds__(256) void out_gemm_kernel(
    const float* __restrict__ agg, const float* __restrict__ Wlin,
    const float* __restrict__ bias, float* __restrict__ out) {
  __shared__ float4 atile[AGG_NODES][4][17];  // [node][hh][g4] padded
  const int tid = threadIdx.x;
  const int node0 = blockIdx.x * AGG_NODES;
  const float4* av = (const float4*)agg;
#pragma unroll
  for (int p = 0; p < 8; ++p) {
    int idx = p * 256 + tid;
    int row = idx >> 6;
    int c = idx & 63;
    if (node0 + row < N_NODES)
      atile[row][c >> 4][c & 15] = av[(size_t)(node0 + row) * 64 + c];
  }
  __syncthreads();
  const int c4 = tid & 63;
  const int ns = tid >> 6;
  const int hh = c4 >> 4;
  const float4* Wv = (const float4*)Wlin;
  float4 acc[8] = {};
  for (int g4 = 0; g4 < 16; ++g4) {
    float4 w0 = Wv[(size_t)(g4 * 4 + 0) * 64 + c4];
    float4 w1 = Wv[(size_t)(g4 * 4 + 1) * 64 + c4];
    float4 w2 = Wv[(size_t)(g4 * 4 + 2) * 64 + c4];
    float4 w3 = Wv[(size_t)(g4 * 4 + 3) * 64 + c4];
#pragma unroll
    for (int n = 0; n < 8; ++n) {
      float4 a = atile[ns * 8 + n][hh][g4];
      acc[n].x += a.x * w0.x + a.y * w1.x + a.z * w2.x + a.w * w3.x;
      acc[n].y += a.x * w0.y + a.y * w1.y + a.z * w2.y + a.w * w3.y;
      acc[n].z += a.x * w0.z + a.y * w1.z + a.z * w2.z + a.w * w3.z;
      acc[n].w += a.x * w0.w + a.y * w1.w + a.z * w2.w + a.w * w3.w;
    }
  }
  float4 bv = ((const float4*)bias)[c4];
#pragma unroll
  for (int n = 0; n < 8; ++n) {
    int node = node0 + ns * 8 + n;
    if (node < N_NODES) {
      float4 o;
      o.x = acc[n].x + bv.x; o.y = acc[n].y + bv.y;
      o.z = acc[n].z + bv.z; o.w = acc[n].w + bv.w;
      ((float4*)out)[(size_t)node * 64 + c4] = o;
    }
  }
}

// ---------------------------------------------------------------------------
extern "C" void kernel_launch(void* const* d_in, const int* in_sizes, int n_in,
                              void* d_out, int out_size, void* d_ws,
                              size_t ws_size, hipStream_t stream) {
  (void)in_sizes; (void)n_in; (void)out_size; (void)ws_size;
  const float* x    = (const float*)d_in[0];
  const int*   ei   = (const int*)d_in[1];
  const float* ew   = (const float*)d_in[2];
  const float* Wlin = (const float*)d_in[3];
  const float* Watt = (const float*)d_in[4];
  const float* bias = (const float*)d_in[5];
  float* out = (float*)d_out;

  const int* srcv = ei;
  const int* dstv = ei + N_EDGES;

  char* ws = (char*)d_ws;
  size_t off = 0;
  auto alloc = [&](size_t bytes) {
    void* p = ws + off;
    off += (bytes + 255) & ~(size_t)255;
    return p;
  };
  float* q         = (float*)alloc((size_t)N_NODES * 256 * 4);  // 51.2 MB
  float* agg       = (float*)alloc((size_t)N_NODES * 256 * 4);  // 51.2 MB
  float* Wt        = (float*)alloc((size_t)64 * 256 * 4);
  int*   deg       = (int*)alloc((size_t)N_NODES * 4);
  int*   offs      = (int*)alloc((size_t)(N_NODES + 1) * 4);
  int*   epos      = (int*)alloc((size_t)N_EDGES * 4);
  int*   csr_src   = (int*)alloc((size_t)PAD_EDGES * 4);
  float* csr_w     = (float*)alloc((size_t)PAD_EDGES * 4);
  int*   blocksums = (int*)alloc((size_t)SCAN_BLOCKS * 4);
  int*   blockoffs = (int*)alloc((size_t)SCAN_BLOCKS * 4);

  hipMemsetAsync(deg, 0, (size_t)N_NODES * 4, stream);
  hipMemsetAsync(csr_src, 0, (size_t)PAD_EDGES * 4, stream);
  hipMemsetAsync(csr_w, 0, (size_t)PAD_EDGES * 4, stream);

  transpose_watt_kernel<<<64, 256, 0, stream>>>(Watt, Wt);
  qgemm_kernel<<<(N_NODES + GEMM_ROWS - 1) / GEMM_ROWS, 256, 0, stream>>>(
      x, Wt, q);
  hist_kernel<<<(N_EDGES + 255) / 256, 256, 0, stream>>>(dstv, deg, epos);
  scan_partials_kernel<<<SCAN_BLOCKS, 256, 0, stream>>>(deg, blocksums);
  scan_blocksums_kernel<<<1, 64, 0, stream>>>(blocksums, blockoffs);
  scan_final_kernel<<<SCAN_BLOCKS, 256, 0, stream>>>(deg, blockoffs, offs);
  scatter_kernel<<<(N_EDGES + 255) / 256, 256, 0, stream>>>(
      srcv, dstv, ew, offs, epos, csr_src, csr_w);
  aggregate_kernel<<<N_NODES / 4, 256, 0, stream>>>(
      q, x, offs, csr_src, csr_w, agg);
  out_gemm_kernel<<<(N_NODES + AGG_NODES - 1) / AGG_NODES, 256, 0, stream>>>(
      agg, Wlin, bias, out);
}

// Round 5
// 212.753 us; speedup vs baseline: 2.1110x; 1.0306x over previous
//
#include <hip/hip_runtime.h>
#include <math.h>

#define N_NODES 50000
#define N_EDGES 800000
#define GEMM_ROWS 32
#define AGG_NODES 32
#define PAD_EDGES (N_EDGES + N_NODES * 7)   // segments padded to x8
#define SCAN_BLOCKS 49                      // ceil(50000 / 1024)
// 0.125 (1/sqrt(64)) * log2(e): folded into Wt so the aggregate loop uses
// exp2 directly and skips per-edge scaling (leaky_relu commutes with c>0).
#define SCALE_FOLD 0.18033688011112042f

// ---------------------------------------------------------------------------
// K1: hist (degree + intra-segment position) + fused W_att transpose/scale.
// Wt[f, h*64+g] = Watt[g, h*64+f] * SCALE_FOLD
// ---------------------------------------------------------------------------
__global__ __launch_bounds__(256) void hist_kernel(
    const int* __restrict__ dst, int* __restrict__ deg, int* __restrict__ epos,
    const float* __restrict__ Watt, float* __restrict__ Wt) {
  int e = blockIdx.x * 256 + threadIdx.x;
  if (blockIdx.x < 64) {  // 16384 transpose elements
    int t = e;
    int g = t & 63;
    int f = (t >> 6) & 63;
    int h = t >> 12;
    Wt[f * 256 + h * 64 + g] = Watt[g * 256 + h * 64 + f] * SCALE_FOLD;
  }
  if (e < N_EDGES) epos[e] = atomicAdd(&deg[dst[e]], 1);
}

// ---------------------------------------------------------------------------
// K2: per-block sums of x8-padded degrees (49 blocks x 256 thr x 4 elems)
// ---------------------------------------------------------------------------
__global__ __launch_bounds__(256) void scan_partials_kernel(
    const int* __restrict__ deg, int* __restrict__ blocksums) {
  __shared__ int red[256];
  const int t = threadIdx.x;
  const int base = blockIdx.x * 1024 + t * 4;
  int s = 0;
  if (base + 3 < N_NODES) {
    int4 d = *(const int4*)(deg + base);
    s = ((d.x + 7) & ~7) + ((d.y + 7) & ~7) + ((d.z + 7) & ~7) +
        ((d.w + 7) & ~7);
  } else {
#pragma unroll
    for (int j = 0; j < 4; ++j)
      if (base + j < N_NODES) s += (deg[base + j] + 7) & ~7;
  }
  red[t] = s;
  __syncthreads();
  for (int d = 128; d > 0; d >>= 1) {
    if (t < d) red[t] += red[t + d];
    __syncthreads();
  }
  if (t == 0) blocksums[blockIdx.x] = red[0];
}

// ---------------------------------------------------------------------------
// K3: final scan (includes the 49-element blocksum scan in-kernel) + offs
// store + pad-slot fill (csr_src=0 / csr_w=0 for padding -> no csr memsets).
// ---------------------------------------------------------------------------
__global__ __launch_bounds__(256) void scan_final_kernel(
    const int* __restrict__ deg, const int* __restrict__ blocksums,
    int* __restrict__ offs, int* __restrict__ csr_src,
    float* __restrict__ csr_w) {
  __shared__ int tsum[256];
  __shared__ int bof_s;
  const int t = threadIdx.x;
  if (t < 64) {  // wave 0: exclusive scan of block sums
    int v = (t < SCAN_BLOCKS) ? blocksums[t] : 0;
    int inc = v;
#pragma unroll
    for (int d = 1; d < 64; d <<= 1) {
      int u = __shfl_up(inc, d);
      if (t >= d) inc += u;
    }
    if (t == (int)blockIdx.x) bof_s = inc - v;
  }
  const int base = blockIdx.x * 1024 + t * 4;
  int r0 = 0, r1 = 0, r2 = 0, r3 = 0;
  if (base + 3 < N_NODES) {
    int4 d = *(const int4*)(deg + base);
    r0 = d.x; r1 = d.y; r2 = d.z; r3 = d.w;
  } else {
    if (base + 0 < N_NODES) r0 = deg[base + 0];
    if (base + 1 < N_NODES) r1 = deg[base + 1];
    if (base + 2 < N_NODES) r2 = deg[base + 2];
    if (base + 3 < N_NODES) r3 = deg[base + 3];
  }
  const int d0 = (r0 + 7) & ~7, d1 = (r1 + 7) & ~7;
  const int d2 = (r2 + 7) & ~7, d3 = (r3 + 7) & ~7;
  const int s = d0 + d1 + d2 + d3;
  tsum[t] = s;
  __syncthreads();
  int inc2 = s;
  for (int d = 1; d < 256; d <<= 1) {
    int u = (t >= d) ? tsum[t - d] : 0;
    __syncthreads();
    inc2 += u;
    tsum[t] = inc2;
    __syncthreads();
  }
  int run = bof_s + inc2 - s;  // exclusive prefix for node base+0
  int o = run;
  if (base + 0 <= N_NODES) offs[base + 0] = o;
  for (int j = r0; j < d0; ++j) { csr_src[o + j] = 0; csr_w[o + j] = 0.f; }
  o += d0;
  if (base + 1 <= N_NODES) offs[base + 1] = o;
  for (int j = r1; j < d1; ++j) { csr_src[o + j] = 0; csr_w[o + j] = 0.f; }
  o += d1;
  if (base + 2 <= N_NODES) offs[base + 2] = o;
  for (int j = r2; j < d2; ++j) { csr_src[o + j] = 0; csr_w[o + j] = 0.f; }
  o += d2;
  if (base + 3 <= N_NODES) offs[base + 3] = o;
  for (int j = r3; j < d3; ++j) { csr_src[o + j] = 0; csr_w[o + j] = 0.f; }
}

// ---------------------------------------------------------------------------
// K4: scatter edges into padded-CSR order (no atomics)
// ---------------------------------------------------------------------------
__global__ __launch_bounds__(256) void scatter_kernel(
    const int* __restrict__ src, const int* __restrict__ dst,
    const float* __restrict__ ew, const int* __restrict__ offs,
    const int* __restrict__ epos, int* __restrict__ csr_src,
    float* __restrict__ csr_w) {
  int e = blockIdx.x * 256 + threadIdx.x;
  if (e >= N_EDGES) return;
  int idx = offs[dst[e]] + epos[e];
  csr_src[idx] = src[e];
  csr_w[idx] = ew[e];
}

// ---------------------------------------------------------------------------
// K5: q = x @ Wt -> [N, 256]; 32 rows/block
// ---------------------------------------------------------------------------
__global__ __launch_bounds__(256) void qgemm_kernel(
    const float* __restrict__ x, const float* __restrict__ Wt,
    float* __restrict__ q) {
  __shared__ float xlds[GEMM_ROWS * 64];  // 8 KB
  const int tid = threadIdx.x;
  const int blk = blockIdx.x;
#pragma unroll
  for (int p = 0; p < 8; ++p) {
    int idx = p * 256 + tid;
    int gidx = blk * (GEMM_ROWS * 64) + idx;
    xlds[idx] = (gidx < N_NODES * 64) ? x[gidx] : 0.f;
  }
  __syncthreads();
  const int c4 = tid & 63;
  const int rg = (tid >> 6) * 8;
  const float4* Wv = (const float4*)Wt;
  float4 acc[8] = {};
  for (int k = 0; k < 64; ++k) {
    float4 w4 = Wv[(size_t)k * 64 + c4];
#pragma unroll
    for (int r = 0; r < 8; ++r) {
      float a = xlds[(rg + r) * 64 + k];
      acc[r].x += a * w4.x; acc[r].y += a * w4.y;
      acc[r].z += a * w4.z; acc[r].w += a * w4.w;
    }
  }
  float4* qv = (float4*)q;
#pragma unroll
  for (int r = 0; r < 8; ++r) {
    int row = blk * GEMM_ROWS + rg + r;
    if (row < N_NODES) qv[(size_t)row * 64 + c4] = acc[r];
  }
}

// ---------------------------------------------------------------------------
// K6: aggregation. One wave/node; 4 edge-groups x 16 lanes.
// Group g handles edge k+g; lane l holds x-chunk l and computes ALL 4 head
// dots (q pre-scaled by 0.125*log2e -> exp2, leaky commutes with c>0).
// Cross-group reduce of (lsum, acc) once at the end.
// ---------------------------------------------------------------------------
__global__ __launch_bounds__(256) void aggregate_kernel(
    const float* __restrict__ q, const float* __restrict__ x,
    const int* __restrict__ offs, const int* __restrict__ csr_src,
    const float* __restrict__ csr_w, float* __restrict__ agg) {
  const int wave = threadIdx.x >> 6;
  const int node = blockIdx.x * 4 + wave;  // grid exact: 50000 = 4*12500
  const int lane = threadIdx.x & 63;
  const int l = lane & 15;
  const int g = lane >> 4;

  const float4* qrow = (const float4*)q + (size_t)node * 64;
  float4 q0 = qrow[l];
  float4 q1 = qrow[16 + l];
  float4 q2 = qrow[32 + l];
  float4 q3 = qrow[48 + l];

  const int s0 = offs[node];
  const int s1 = offs[node + 1];
  const float4* xv = (const float4*)x;

  float4 acc0 = {0.f, 0.f, 0.f, 0.f}, acc1 = {0.f, 0.f, 0.f, 0.f};
  float4 acc2 = {0.f, 0.f, 0.f, 0.f}, acc3 = {0.f, 0.f, 0.f, 0.f};
  float ls0 = 0.f, ls1 = 0.f, ls2 = 0.f, ls3 = 0.f;

  for (int k = s0; k < s1; k += 8) {
    int jA = csr_src[k + g];
    int jB = csr_src[k + 4 + g];
    float wA = csr_w[k + g];
    float wB = csr_w[k + 4 + g];
    float4 aA = xv[(size_t)jA * 16 + l];
    float4 aB = xv[(size_t)jB * 16 + l];

    float dA0 = aA.x * q0.x + aA.y * q0.y + aA.z * q0.z + aA.w * q0.w;
    float dA1 = aA.x * q1.x + aA.y * q1.y + aA.z * q1.z + aA.w * q1.w;
    float dA2 = aA.x * q2.x + aA.y * q2.y + aA.z * q2.z + aA.w * q2.w;
    float dA3 = aA.x * q3.x + aA.y * q3.y + aA.z * q3.z + aA.w * q3.w;
    float dB0 = aB.x * q0.x + aB.y * q0.y + aB.z * q0.z + aB.w * q0.w;
    float dB1 = aB.x * q1.x + aB.y * q1.y + aB.z * q1.z + aB.w * q1.w;
    float dB2 = aB.x * q2.x + aB.y * q2.y + aB.z * q2.z + aB.w * q2.w;
    float dB3 = aB.x * q3.x + aB.y * q3.y + aB.z * q3.z + aB.w * q3.w;
#pragma unroll
    for (int dd = 1; dd <= 8; dd <<= 1) {  // 16-lane group reduction (DPP)
      dA0 += __shfl_xor(dA0, dd); dA1 += __shfl_xor(dA1, dd);
      dA2 += __shfl_xor(dA2, dd); dA3 += __shfl_xor(dA3, dd);
      dB0 += __shfl_xor(dB0, dd); dB1 += __shfl_xor(dB1, dd);
      dB2 += __shfl_xor(dB2, dd); dB3 += __shfl_xor(dB3, dd);
    }
    dA0 = fmaxf(dA0, 0.2f * dA0);  // leaky_relu (pre-scaled domain)
    dA1 = fmaxf(dA1, 0.2f * dA1);
    dA2 = fmaxf(dA2, 0.2f * dA2);
    dA3 = fmaxf(dA3, 0.2f * dA3);
    dB0 = fmaxf(dB0, 0.2f * dB0);
    dB1 = fmaxf(dB1, 0.2f * dB1);
    dB2 = fmaxf(dB2, 0.2f * dB2);
    dB3 = fmaxf(dB3, 0.2f * dB3);
    float pA0 = exp2f(dA0) * wA, pA1 = exp2f(dA1) * wA;
    float pA2 = exp2f(dA2) * wA, pA3 = exp2f(dA3) * wA;
    float pB0 = exp2f(dB0) * wB, pB1 = exp2f(dB1) * wB;
    float pB2 = exp2f(dB2) * wB, pB3 = exp2f(dB3) * wB;
    ls0 += pA0 + pB0; ls1 += pA1 + pB1;
    ls2 += pA2 + pB2; ls3 += pA3 + pB3;
    acc0.x += pA0 * aA.x + pB0 * aB.x; acc0.y += pA0 * aA.y + pB0 * aB.y;
    acc0.z += pA0 * aA.z + pB0 * aB.z; acc0.w += pA0 * aA.w + pB0 * aB.w;
    acc1.x += pA1 * aA.x + pB1 * aB.x; acc1.y += pA1 * aA.y + pB1 * aB.y;
    acc1.z += pA1 * aA.z + pB1 * aB.z; acc1.w += pA1 * aA.w + pB1 * aB.w;
    acc2.x += pA2 * aA.x + pB2 * aB.x; acc2.y += pA2 * aA.y + pB2 * aB.y;
    acc2.z += pA2 * aA.z + pB2 * aB.z; acc2.w += pA2 * aA.w + pB2 * aB.w;
    acc3.x += pA3 * aA.x + pB3 * aB.x; acc3.y += pA3 * aA.y + pB3 * aB.y;
    acc3.z += pA3 * aA.z + pB3 * aB.z; acc3.w += pA3 * aA.w + pB3 * aB.w;
  }
  // cross-group reduction (lanes g differ -> xor 16, 32)
#pragma unroll
  for (int dd = 16; dd <= 32; dd <<= 1) {
    ls0 += __shfl_xor(ls0, dd); ls1 += __shfl_xor(ls1, dd);
    ls2 += __shfl_xor(ls2, dd); ls3 += __shfl_xor(ls3, dd);
    acc0.x += __shfl_xor(acc0.x, dd); acc0.y += __shfl_xor(acc0.y, dd);
    acc0.z += __shfl_xor(acc0.z, dd); acc0.w += __shfl_xor(acc0.w, dd);
    acc1.x += __shfl_xor(acc1.x, dd); acc1.y += __shfl_xor(acc1.y, dd);
    acc1.z += __shfl_xor(acc1.z, dd); acc1.w += __shfl_xor(acc1.w, dd);
    acc2.x += __shfl_xor(acc2.x, dd); acc2.y += __shfl_xor(acc2.y, dd);
    acc2.z += __shfl_xor(acc2.z, dd); acc2.w += __shfl_xor(acc2.w, dd);
    acc3.x += __shfl_xor(acc3.x, dd); acc3.y += __shfl_xor(acc3.y, dd);
    acc3.z += __shfl_xor(acc3.z, dd); acc3.w += __shfl_xor(acc3.w, dd);
  }
  float lsum = (g == 0) ? ls0 : (g == 1) ? ls1 : (g == 2) ? ls2 : ls3;
  float4 av = (g == 0) ? acc0 : (g == 1) ? acc1 : (g == 2) ? acc2 : acc3;
  float inv = 1.f / (lsum + 1e-16f);
  float4 o4;
  o4.x = av.x * inv; o4.y = av.y * inv;
  o4.z = av.z * inv; o4.w = av.w * inv;
  ((float4*)agg)[(size_t)node * 64 + lane] = o4;  // lane = g*16+l -> head g
}

// ---------------------------------------------------------------------------
// K7: out[n, :] = agg[n, block-diag] @ Wlin + bias. 32 nodes/block.
// ---------------------------------------------------------------------------
__global__ __launch_bounds__(256) void out_gemm_kernel(
    const float* __restrict__ agg, const float* __restrict__ Wlin,
    const float* __restrict__ bias, float* __restrict__ out) {
  __shared__ float4 atile[AGG_NODES][4][17];  // [node][hh][g4] padded
  const int tid = threadIdx.x;
  const int node0 = blockIdx.x * AGG_NODES;
  const float4* av = (const float4*)agg;
#pragma unroll
  for (int p = 0; p < 8; ++p) {
    int idx = p * 256 + tid;
    int row = idx >> 6;
    int c = idx & 63;
    if (node0 + row < N_NODES)
      atile[row][c >> 4][c & 15] = av[(size_t)(node0 + row) * 64 + c];
  }
  __syncthreads();
  const int c4 = tid & 63;
  const int ns = tid >> 6;
  const int hh = c4 >> 4;
  const float4* Wv = (const float4*)Wlin;
  float4 acc[8] = {};
  for (int g4 = 0; g4 < 16; ++g4) {
    float4 w0 = Wv[(size_t)(g4 * 4 + 0) * 64 + c4];
    float4 w1 = Wv[(size_t)(g4 * 4 + 1) * 64 + c4];
    float4 w2 = Wv[(size_t)(g4 * 4 + 2) * 64 + c4];
    float4 w3 = Wv[(size_t)(g4 * 4 + 3) * 64 + c4];
#pragma unroll
    for (int n = 0; n < 8; ++n) {
      float4 a = atile[ns * 8 + n][hh][g4];
      acc[n].x += a.x * w0.x + a.y * w1.x + a.z * w2.x + a.w * w3.x;
      acc[n].y += a.x * w0.y + a.y * w1.y + a.z * w2.y + a.w * w3.y;
      acc[n].z += a.x * w0.z + a.y * w1.z + a.z * w2.z + a.w * w3.z;
      acc[n].w += a.x * w0.w + a.y * w1.w + a.z * w2.w + a.w * w3.w;
    }
  }
  float4 bv = ((const float4*)bias)[c4];
#pragma unroll
  for (int n = 0; n < 8; ++n) {
    int node = node0 + ns * 8 + n;
    if (node < N_NODES) {
      float4 o;
      o.x = acc[n].x + bv.x; o.y = acc[n].y + bv.y;
      o.z = acc[n].z + bv.z; o.w = acc[n].w + bv.w;
      ((float4*)out)[(size_t)node * 64 + c4] = o;
    }
  }
}

// ---------------------------------------------------------------------------
extern "C" void kernel_launch(void* const* d_in, const int* in_sizes, int n_in,
                              void* d_out, int out_size, void* d_ws,
                              size_t ws_size, hipStream_t stream) {
  (void)in_sizes; (void)n_in; (void)out_size; (void)ws_size;
  const float* x    = (const float*)d_in[0];
  const int*   ei   = (const int*)d_in[1];
  const float* ew   = (const float*)d_in[2];
  const float* Wlin = (const float*)d_in[3];
  const float* Watt = (const float*)d_in[4];
  const float* bias = (const float*)d_in[5];
  float* out = (float*)d_out;

  const int* srcv = ei;
  const int* dstv = ei + N_EDGES;

  char* ws = (char*)d_ws;
  size_t off = 0;
  auto alloc = [&](size_t bytes) {
    void* p = ws + off;
    off += (bytes + 255) & ~(size_t)255;
    return p;
  };
  float* q         = (float*)alloc((size_t)N_NODES * 256 * 4);  // 51.2 MB
  float* agg       = (float*)alloc((size_t)N_NODES * 256 * 4);  // 51.2 MB
  float* Wt        = (float*)alloc((size_t)64 * 256 * 4);
  int*   deg       = (int*)alloc((size_t)N_NODES * 4);
  int*   offs      = (int*)alloc((size_t)(N_NODES + 1) * 4);
  int*   epos      = (int*)alloc((size_t)N_EDGES * 4);
  int*   csr_src   = (int*)alloc((size_t)PAD_EDGES * 4);
  float* csr_w     = (float*)alloc((size_t)PAD_EDGES * 4);
  int*   blocksums = (int*)alloc((size_t)SCAN_BLOCKS * 4);

  hipMemsetAsync(deg, 0, (size_t)N_NODES * 4, stream);

  hist_kernel<<<(N_EDGES + 255) / 256, 256, 0, stream>>>(dstv, deg, epos,
                                                         Watt, Wt);
  scan_partials_kernel<<<SCAN_BLOCKS, 256, 0, stream>>>(deg, blocksums);
  scan_final_kernel<<<SCAN_BLOCKS, 256, 0, stream>>>(deg, blocksums, offs,
                                                     csr_src, csr_w);
  scatter_kernel<<<(N_EDGES + 255) / 256, 256, 0, stream>>>(
      srcv, dstv, ew, offs, epos, csr_src, csr_w);
  qgemm_kernel<<<(N_NODES + GEMM_ROWS - 1) / GEMM_ROWS, 256, 0, stream>>>(
      x, Wt, q);
  aggregate_kernel<<<N_NODES / 4, 256, 0, stream>>>(
      q, x, offs, csr_src, csr_w, agg);
  out_gemm_kernel<<<(N_NODES + AGG_NODES - 1) / AGG_NODES, 256, 0, stream>>>(
      agg, Wlin, bias, out);
}